// Round 1
// baseline (326.189 us; speedup 1.0000x reference)
//
#include <hip/hip_runtime.h>

// Ranking-loss scalar reduction:
//   loss = 0.2 * (pos*sum_neg - neg*sum_pos) / (pos*neg)
// Needs sum(y), sum(y*lab), sum(lab) over N=32M. Memory-bound: 256 MB read.
// All accumulation in double: final expression is a catastrophic cancellation
// (terms ~1e11, result ~3e5 scaled) and the harness threshold is ~2% relative
// to a ~3e-5 loss, so fp32 accumulation error (~O(100) on a 32M-element sum)
// would blow the budget; fp64 keeps sum error << 1.

__global__ void aux_loss_reduce(const float* __restrict__ y,
                                const int* __restrict__ lab,
                                double* __restrict__ acc, int n) {
    const int n4 = n >> 2;
    const float4* __restrict__ y4 = (const float4*)y;
    const int4* __restrict__ l4 = (const int4*)lab;

    double s_all = 0.0, s_pos = 0.0;
    int cnt = 0;

    int idx = blockIdx.x * blockDim.x + threadIdx.x;
    int stride = gridDim.x * blockDim.x;

    for (int i = idx; i < n4; i += stride) {
        float4 v = y4[i];
        int4 l = l4[i];
        s_all += (double)v.x + (double)v.y + (double)v.z + (double)v.w;
        s_pos += (l.x ? (double)v.x : 0.0) + (l.y ? (double)v.y : 0.0)
               + (l.z ? (double)v.z : 0.0) + (l.w ? (double)v.w : 0.0);
        cnt += l.x + l.y + l.z + l.w;   // labels are 0/1
    }
    // scalar tail (N=32M is divisible by 4, but stay generic)
    for (int i = (n4 << 2) + idx; i < n; i += stride) {
        float v = y[i];
        int l = lab[i];
        s_all += (double)v;
        if (l) { s_pos += (double)v; cnt += l; }
    }

    double c = (double)cnt;

    // wave-level butterfly reduce (64 lanes)
    for (int off = 32; off > 0; off >>= 1) {
        s_all += __shfl_down(s_all, off);
        s_pos += __shfl_down(s_pos, off);
        c     += __shfl_down(c, off);
    }

    // cross-wave via LDS (256-thread block = 4 waves)
    __shared__ double sh_all[4], sh_pos[4], sh_cnt[4];
    int wave = threadIdx.x >> 6;
    int lane = threadIdx.x & 63;
    if (lane == 0) { sh_all[wave] = s_all; sh_pos[wave] = s_pos; sh_cnt[wave] = c; }
    __syncthreads();

    if (threadIdx.x == 0) {
        double a = 0.0, p = 0.0, cc = 0.0;
        int nw = (blockDim.x + 63) >> 6;
        for (int w = 0; w < nw; ++w) { a += sh_all[w]; p += sh_pos[w]; cc += sh_cnt[w]; }
        // one fp64 device-scope atomic per block (2048 total — negligible contention)
        atomicAdd(&acc[0], a);
        atomicAdd(&acc[1], p);
        atomicAdd(&acc[2], cc);
    }
}

__global__ void aux_loss_finalize(const double* __restrict__ acc,
                                  float* __restrict__ out, double n_total) {
    double sum_all = acc[0];
    double sum_pos = acc[1];
    double pos     = acc[2];
    double neg     = n_total - pos;
    double sum_neg = sum_all - sum_pos;
    double loss = 0.0;
    if (pos > 0.0 && neg > 0.0) {
        loss = 0.2 * (pos * sum_neg - neg * sum_pos) / (pos * neg);
    }
    out[0] = (float)loss;
}

extern "C" void kernel_launch(void* const* d_in, const int* in_sizes, int n_in,
                              void* d_out, int out_size, void* d_ws, size_t ws_size,
                              hipStream_t stream) {
    const float* y  = (const float*)d_in[0];
    const int* lab  = (const int*)d_in[1];
    int n = in_sizes[0];

    double* acc = (double*)d_ws;          // 3 doubles of scratch
    hipMemsetAsync(acc, 0, 3 * sizeof(double), stream);  // ws is poisoned 0xAA each call

    const int block = 256;
    const int grid  = 2048;               // 32 waves/CU across 256 CUs — full occupancy
    aux_loss_reduce<<<grid, block, 0, stream>>>(y, lab, acc, n);
    aux_loss_finalize<<<1, 1, 0, stream>>>(acc, (float*)d_out, (double)n);
}

// Round 2
// 274.910 us; speedup vs baseline: 1.1865x; 1.1865x over previous
//
#include <hip/hip_runtime.h>

// Ranking-loss scalar reduction:
//   loss = 0.2 * (pos*sum_neg - neg*sum_pos) / (pos*neg)
// Needs sum(y), sum(y*lab), sum(lab) over N=32M floats/ints (256 MB read).
//
// R1 lesson: 2048 blocks x 3 fp64 atomicAdds on the SAME 3 addresses
// serialized through the coherence fabric (~148us, independent of L3
// warmth; WRITE_SIZE 192KB == 6144 x 32B atomic lines). Replaced with
// per-block partial stores (no contention) + a tiny stage-2 kernel.
//
// fp64 accumulation throughout: the final expression is a catastrophic
// cancellation (terms ~1e11, result tiny) and the harness threshold is
// ~2% of a ~3e-5 loss; fp64 keeps sum error << 1e-9.

#define NBLK 2048

__global__ void aux_loss_reduce(const float* __restrict__ y,
                                const int* __restrict__ lab,
                                double* __restrict__ part, int n) {
    const int n4 = n >> 2;
    const float4* __restrict__ y4 = (const float4*)y;
    const int4* __restrict__ l4 = (const int4*)lab;

    double s_all = 0.0, s_pos = 0.0;
    int cnt = 0;

    const int idx = blockIdx.x * blockDim.x + threadIdx.x;
    const int stride = gridDim.x * blockDim.x;

    // 2x unrolled grid-stride: two independent (float4,int4) load pairs in
    // flight per iteration for memory-level parallelism.
    int i = idx;
    for (; i + stride < n4; i += 2 * stride) {
        float4 va = y4[i];
        int4 la = l4[i];
        float4 vb = y4[i + stride];
        int4 lb = l4[i + stride];

        s_all += (double)va.x + (double)va.y + (double)va.z + (double)va.w;
        s_pos += (la.x ? (double)va.x : 0.0) + (la.y ? (double)va.y : 0.0)
               + (la.z ? (double)va.z : 0.0) + (la.w ? (double)va.w : 0.0);
        cnt += la.x + la.y + la.z + la.w;

        s_all += (double)vb.x + (double)vb.y + (double)vb.z + (double)vb.w;
        s_pos += (lb.x ? (double)vb.x : 0.0) + (lb.y ? (double)vb.y : 0.0)
               + (lb.z ? (double)vb.z : 0.0) + (lb.w ? (double)vb.w : 0.0);
        cnt += lb.x + lb.y + lb.z + lb.w;
    }
    for (; i < n4; i += stride) {
        float4 v = y4[i];
        int4 l = l4[i];
        s_all += (double)v.x + (double)v.y + (double)v.z + (double)v.w;
        s_pos += (l.x ? (double)v.x : 0.0) + (l.y ? (double)v.y : 0.0)
               + (l.z ? (double)v.z : 0.0) + (l.w ? (double)v.w : 0.0);
        cnt += l.x + l.y + l.z + l.w;
    }
    // scalar tail (N divisible by 4 here, but stay generic)
    for (int j = (n4 << 2) + idx; j < n; j += stride) {
        float v = y[j];
        int l = lab[j];
        s_all += (double)v;
        if (l) { s_pos += (double)v; cnt += l; }
    }

    double c = (double)cnt;

    // wave-level reduce (64 lanes)
    for (int off = 32; off > 0; off >>= 1) {
        s_all += __shfl_down(s_all, off);
        s_pos += __shfl_down(s_pos, off);
        c     += __shfl_down(c, off);
    }

    // cross-wave via LDS (256-thread block = 4 waves)
    __shared__ double sh_all[4], sh_pos[4], sh_cnt[4];
    const int wave = threadIdx.x >> 6;
    const int lane = threadIdx.x & 63;
    if (lane == 0) { sh_all[wave] = s_all; sh_pos[wave] = s_pos; sh_cnt[wave] = c; }
    __syncthreads();

    if (threadIdx.x == 0) {
        double a = 0.0, p = 0.0, cc = 0.0;
        for (int w = 0; w < 4; ++w) { a += sh_all[w]; p += sh_pos[w]; cc += sh_cnt[w]; }
        // SoA partials: contention-free plain stores, coalesced stage-2 reads
        part[blockIdx.x]            = a;
        part[NBLK + blockIdx.x]     = p;
        part[2 * NBLK + blockIdx.x] = cc;
    }
}

__global__ void aux_loss_stage2(const double* __restrict__ part,
                                float* __restrict__ out, double n_total) {
    double a = 0.0, p = 0.0, cc = 0.0;
    for (int i = threadIdx.x; i < NBLK; i += blockDim.x) {
        a  += part[i];
        p  += part[NBLK + i];
        cc += part[2 * NBLK + i];
    }
    for (int off = 32; off > 0; off >>= 1) {
        a  += __shfl_down(a, off);
        p  += __shfl_down(p, off);
        cc += __shfl_down(cc, off);
    }
    __shared__ double sh_a[4], sh_p[4], sh_c[4];
    const int wave = threadIdx.x >> 6;
    const int lane = threadIdx.x & 63;
    if (lane == 0) { sh_a[wave] = a; sh_p[wave] = p; sh_c[wave] = cc; }
    __syncthreads();

    if (threadIdx.x == 0) {
        double sum_all = 0.0, sum_pos = 0.0, pos = 0.0;
        for (int w = 0; w < 4; ++w) { sum_all += sh_a[w]; sum_pos += sh_p[w]; pos += sh_c[w]; }
        double neg = n_total - pos;
        double sum_neg = sum_all - sum_pos;
        double loss = 0.0;
        if (pos > 0.0 && neg > 0.0) {
            loss = 0.2 * (pos * sum_neg - neg * sum_pos) / (pos * neg);
        }
        out[0] = (float)loss;
    }
}

extern "C" void kernel_launch(void* const* d_in, const int* in_sizes, int n_in,
                              void* d_out, int out_size, void* d_ws, size_t ws_size,
                              hipStream_t stream) {
    const float* y = (const float*)d_in[0];
    const int* lab = (const int*)d_in[1];
    int n = in_sizes[0];

    double* part = (double*)d_ws;  // 3 * NBLK doubles = 48 KB of scratch
    // No memset needed: every slot is unconditionally written by stage 1.

    aux_loss_reduce<<<NBLK, 256, 0, stream>>>(y, lab, part, n);
    aux_loss_stage2<<<1, 256, 0, stream>>>(part, (float*)d_out, (double)n);
}